// Round 1
// 354.684 us; speedup vs baseline: 1.2019x; 1.2019x over previous
//
#include <hip/hip_runtime.h>
#include <stdint.h>

typedef unsigned short ushort;
typedef __attribute__((ext_vector_type(8))) short bf16x8;
typedef __attribute__((ext_vector_type(4))) float f32x4;

// ---- bf16 helpers (bit-level) ----
__device__ __forceinline__ float b2f(ushort u) {
    return __uint_as_float(((unsigned)u) << 16);
}
__device__ __forceinline__ ushort f2b(float f) {
    unsigned u = __float_as_uint(f);
    u += 0x7fff + ((u >> 16) & 1);   // round-to-nearest-even
    return (ushort)(u >> 16);
}
__device__ __forceinline__ ushort f2b_fast(float f) {   // round-half-up (positive vals)
    return (ushort)((__float_as_uint(f) + 0x8000u) >> 16);
}

// Problem constants: B=4, N=2048, C=1024, H=16, D=64, M = B*N = 8192
#define SEQN 2048
#define EMB  1024
#define NH   16
#define HD   64
#define BHSTRIDE (SEQN * HD)   // 131072 elems per (b,h) plane

// async global->LDS, 16B per lane; LDS dest = wave-uniform base + lane*16
__device__ __forceinline__ void gload16(const ushort* g, ushort* l) {
    __builtin_amdgcn_global_load_lds(
        (const __attribute__((address_space(1))) unsigned int*)g,
        (__attribute__((address_space(3))) unsigned int*)l, 16, 0, 0);
}

// =====================================================================
// Kernel A: fp32 -> bf16 pre-conversion (x), grid exact: 4096 x 256
// 8 elems / thread (32B load, 16B store).
// =====================================================================
__global__ __launch_bounds__(256) void conv_x(
        const float* __restrict__ s, ushort* __restrict__ d) {
    const size_t i = (size_t)blockIdx.x * 256 + threadIdx.x;
    float4 a = ((const float4*)s)[2 * i];
    float4 b = ((const float4*)s)[2 * i + 1];
    ushort pk[8] = {f2b(a.x), f2b(a.y), f2b(a.z), f2b(a.w),
                    f2b(b.x), f2b(b.y), f2b(b.z), f2b(b.w)};
    ((uint4*)d)[i] = *(uint4*)pk;
}

// Kernel B: convert the 4 weight matrices into one contiguous bf16 buffer
// Wb = [Wq; Wk; Wv; Wo], each 1024x1024.  grid (512, 4) x 256.
__global__ __launch_bounds__(256) void conv_w4(
        const float* __restrict__ W0, const float* __restrict__ W1,
        const float* __restrict__ W2, const float* __restrict__ W3,
        ushort* __restrict__ d) {
    const float* s = (blockIdx.y == 0) ? W0 : (blockIdx.y == 1) ? W1
                   : (blockIdx.y == 2) ? W2 : W3;
    ushort* dst = d + ((size_t)blockIdx.y << 20);
    const size_t i = (size_t)blockIdx.x * 256 + threadIdx.x;
    float4 a = ((const float4*)s)[2 * i];
    float4 b = ((const float4*)s)[2 * i + 1];
    ushort pk[8] = {f2b(a.x), f2b(a.y), f2b(a.z), f2b(a.w),
                    f2b(b.x), f2b(b.y), f2b(b.z), f2b(b.w)};
    ((uint4*)dst)[i] = *(uint4*)pk;
}

// =====================================================================
// Kernel 0: permuted bias table.
// E_perm[qt][kv][q'] = exp(wd*dist[qt*16+q'][kv] + bd), bf16.
// =====================================================================
__global__ __launch_bounds__(256) void bias_exp_perm(
        const float* __restrict__ dist, const float* __restrict__ dw,
        const float* __restrict__ db, ushort* __restrict__ E) {
    const float wd = dw[0], bd = db[0];
    const int kv = blockIdx.x * 256 + threadIdx.x;
    const int qt = blockIdx.y;
    ushort pk[16];
#pragma unroll
    for (int qq = 0; qq < 16; qq++)
        pk[qq] = f2b(__expf(fmaf(wd, dist[(size_t)(qt * 16 + qq) * SEQN + kv], bd)));
    ushort* dst = E + ((size_t)qt << 15) + (size_t)kv * 16;
    *(uint4*)dst       = *(uint4*)&pk[0];
    *(uint4*)(dst + 8) = *(uint4*)&pk[8];
}

// =====================================================================
// Shared m97-style mainloop pieces: 128x128 tile, BK=32, bf16 inputs,
// LDS linear [128][32] filled by global_load_lds width=16.
// Each wave stages 2 x 1KB chunks per matrix per k-step.
// =====================================================================
#define LDSZ (128 * 32)   // shorts per tile buffer

// =====================================================================
// Kernel 1: fused QKV projection.  grid = (M/128, 3*8)
// A = xb bf16 [8192][1024], W = Wb plane (bf16 [1024][1024], torch [o][c]).
// q (PRE-SCALED by 1/8), k -> [B,H,N,D] bf16; v -> [B,H,D,N] bf16.
// =====================================================================
__global__ __launch_bounds__(256) void gemm_qkv(
        const ushort* __restrict__ xb, const ushort* __restrict__ Wb,
        const float* __restrict__ bq, const float* __restrict__ bk,
        const float* __restrict__ bv,
        ushort* __restrict__ qb, ushort* __restrict__ kb,
        ushort* __restrict__ vT) {
    __shared__ ushort As[LDSZ];
    __shared__ ushort Bs[LDSZ];
    const int m0   = blockIdx.x * 128;
    const int nt   = blockIdx.y;           // 0..23
    const int wsel = nt >> 3;
    const int n0   = (nt & 7) * 128;
    const ushort* W    = Wb + ((size_t)wsel << 20);
    const float* bias  = (wsel == 0) ? bq : (wsel == 1) ? bk : bv;

    const int t = threadIdx.x, lane = t & 63, wave = t >> 6;
    const int ln = lane & 15, quad = lane >> 4;
    const int wm = wave & 1, wn = wave >> 1;

    // staging descriptors: 2 slots/wave/matrix; chunk e = wave*128+s*64+lane
    const int e0 = wave * 128 + lane;
    const int e1 = e0 + 64;
    const ushort* gA0 = xb + (size_t)(m0 + (e0 >> 2)) * 1024 + (e0 & 3) * 8;
    const ushort* gA1 = xb + (size_t)(m0 + (e1 >> 2)) * 1024 + (e1 & 3) * 8;
    const ushort* gB0 = W  + (size_t)(n0 + (e0 >> 2)) * 1024 + (e0 & 3) * 8;
    const ushort* gB1 = W  + (size_t)(n0 + (e1 >> 2)) * 1024 + (e1 & 3) * 8;
    ushort* lA0 = As + wave * 1024;     // wave-uniform LDS bases
    ushort* lA1 = lA0 + 512;
    ushort* lB0 = Bs + wave * 1024;
    ushort* lB1 = lB0 + 512;

    f32x4 acc[4][4];
#pragma unroll
    for (int i = 0; i < 4; i++)
#pragma unroll
        for (int j = 0; j < 4; j++) acc[i][j] = (f32x4){0.f, 0.f, 0.f, 0.f};

    for (int k0 = 0; k0 < 1024; k0 += 32) {
        __syncthreads();                 // prev iter's LDS reads complete
        gload16(gA0 + k0, lA0);
        gload16(gA1 + k0, lA1);
        gload16(gB0 + k0, lB0);
        gload16(gB1 + k0, lB1);
        __syncthreads();                 // vmcnt(0) drain + barrier
        bf16x8 af[4], bfr[4];
#pragma unroll
        for (int i = 0; i < 4; i++)
            af[i]  = *(bf16x8*)&As[(wm * 64 + i * 16 + ln) * 32 + quad * 8];
#pragma unroll
        for (int j = 0; j < 4; j++)
            bfr[j] = *(bf16x8*)&Bs[(wn * 64 + j * 16 + ln) * 32 + quad * 8];
#pragma unroll
        for (int i = 0; i < 4; i++)
#pragma unroll
            for (int j = 0; j < 4; j++)
                acc[i][j] = __builtin_amdgcn_mfma_f32_16x16x32_bf16(
                                af[i], bfr[j], acc[i][j], 0, 0, 0);
    }

    if (wsel < 2) {
        ushort* dst = (wsel == 0) ? qb : kb;
        const float scale = (wsel == 0) ? 0.125f : 1.0f;   // q pre-scaled
#pragma unroll
        for (int j = 0; j < 4; j++) {
            const int o  = n0 + wn * 64 + j * 16 + ln;     // output channel
            const float bval = bias[o];
            const int h = o >> 6, d = o & 63;
#pragma unroll
            for (int i = 0; i < 4; i++) {
                const int mg = m0 + wm * 64 + i * 16 + quad * 4;
#pragma unroll
                for (int r = 0; r < 4; r++) {
                    const int m  = mg + r;
                    const int b  = m >> 11;          // / 2048
                    const int ns = m & 2047;
                    dst[(size_t)(b * NH + h) * BHSTRIDE + (size_t)ns * HD + d] =
                        f2b((acc[i][j][r] + bval) * scale);
                }
            }
        }
    } else {
        // V transposed: vT[(b*NH+h)*BHSTRIDE + d*SEQN + n]
#pragma unroll
        for (int j = 0; j < 4; j++) {
            const int o  = n0 + wn * 64 + j * 16 + ln;
            const float bval = bias[o];
            const int h = o >> 6, d = o & 63;
#pragma unroll
            for (int i = 0; i < 4; i++) {
                const int mg = m0 + wm * 64 + i * 16 + quad * 4;
                const int b  = mg >> 11;
                const int ns = mg & 2047;           // 4-aligned, same batch
                ushort pk[4];
#pragma unroll
                for (int r = 0; r < 4; r++) pk[r] = f2b(acc[i][j][r] + bval);
                *(uint2*)&vT[(size_t)(b * NH + h) * BHSTRIDE +
                             (size_t)d * SEQN + ns] = *(uint2*)&pk[0];
            }
        }
    }
}

// =====================================================================
// Kernel 2: distance-biased attention (unchanged this round).
// =====================================================================
__global__ __launch_bounds__(256) void attn(
        ushort* q,                     // aliased in/out (no restrict)
        const ushort* __restrict__ k,
        const ushort* __restrict__ vT,
        const ushort* __restrict__ E) {
    __shared__ short Ks[64 * 72];      // [kv][d]
    __shared__ short Vs[64 * 72];      // [d][kv]
    __shared__ short Ps[4][32 * 72];   // per-wave P tile [q-row][kv]
    const int t = threadIdx.x, lane = t & 63, wave = t >> 6;
    const int ln = lane & 15, quad = lane >> 4;
    const int h = blockIdx.y, b = blockIdx.z;
    const int bh = b * NH + h;
    const int qw0 = blockIdx.x * 128 + wave * 32;   // this wave's 32 q-rows
    const int qt0 = qw0 >> 4;                       // q-tile index for E

    ushort* qp = q + (size_t)bh * BHSTRIDE;
    const ushort* kp = k  + (size_t)bh * BHSTRIDE;
    const ushort* vp = vT + (size_t)bh * BHSTRIDE;

    // staging coords: thread t covers row sr, 16-short chunk sc
    const int sr = t >> 2;           // 0..63
    const int sc = (t & 3) * 16;     // 0,16,32,48

    // Q fragments (A-operand): registers for the whole kv loop
    bf16x8 qf[2][2];
#pragma unroll
    for (int qi = 0; qi < 2; qi++)
#pragma unroll
        for (int ks = 0; ks < 2; ks++)
            qf[qi][ks] = *(const bf16x8*)(qp + (size_t)(qw0 + qi * 16 + ln) * HD
                                          + ks * 32 + quad * 8);

    f32x4 O[2][4];
#pragma unroll
    for (int qi = 0; qi < 2; qi++)
#pragma unroll
        for (int nd = 0; nd < 4; nd++) O[qi][nd] = (f32x4){0.f, 0.f, 0.f, 0.f};
    float lsum[2][4] = {{0.f,0.f,0.f,0.f},{0.f,0.f,0.f,0.f}};
    short* myp = &Ps[wave][0];

    // ---- prologue: load tile 0 into staging registers ----
    uint4 krg0 = *(const uint4*)(kp + (size_t)sr * HD + sc);
    uint4 krg1 = *(const uint4*)(kp + (size_t)sr * HD + sc + 8);
    uint4 vrg0 = *(const uint4*)(vp + (size_t)sr * SEQN + sc);
    uint4 vrg1 = *(const uint4*)(vp + (size_t)sr * SEQN + sc + 8);

    for (int kt = 0; kt < 32; kt++) {
        const int kv0 = kt * 64;
        __syncthreads();             // prev iteration's LDS reads complete
        *(uint4*)&Ks[sr * 72 + sc]     = krg0;
        *(uint4*)&Ks[sr * 72 + sc + 8] = krg1;
        *(uint4*)&Vs[sr * 72 + sc]     = vrg0;
        *(uint4*)&Vs[sr * 72 + sc + 8] = vrg1;
        __syncthreads();             // tiles visible to all waves
        // ---- prefetch next tile (latency hides under compute below) ----
        const int kvn = (kv0 + 64) & 2047;   // wrap: last prefetch harmless
        krg0 = *(const uint4*)(kp + (size_t)(kvn + sr) * HD + sc);
        krg1 = *(const uint4*)(kp + (size_t)(kvn + sr) * HD + sc + 8);
        vrg0 = *(const uint4*)(vp + (size_t)sr * SEQN + kvn + sc);
        vrg1 = *(const uint4*)(vp + (size_t)sr * SEQN + kvn + sc + 8);
        // ---- E values (coalesced uint2 from permuted table) ----
        uint2 ev2[2][4];
#pragma unroll
        for (int qi = 0; qi < 2; qi++) {
            const size_t ebase = ((size_t)(qt0 + qi)) << 15;
#pragma unroll
            for (int kvb = 0; kvb < 4; kvb++)
                ev2[qi][kvb] = *(const uint2*)(E + ebase +
                    (size_t)(kv0 + kvb * 16 + ln) * 16 + quad * 4);
        }
        // ---- K fragments from LDS (shared across qi) ----
        bf16x8 kf0[4], kf1[4];
#pragma unroll
        for (int kvb = 0; kvb < 4; kvb++) {
            kf0[kvb] = *(bf16x8*)&Ks[(kvb * 16 + ln) * 72 + quad * 8];
            kf1[kvb] = *(bf16x8*)&Ks[(kvb * 16 + ln) * 72 + 32 + quad * 8];
        }
        // ---- S = Q K^T ----
        f32x4 s[2][4];
#pragma unroll
        for (int qi = 0; qi < 2; qi++)
#pragma unroll
            for (int kvb = 0; kvb < 4; kvb++) {
                f32x4 z = (f32x4){0.f, 0.f, 0.f, 0.f};
                z = __builtin_amdgcn_mfma_f32_16x16x32_bf16(qf[qi][0], kf0[kvb], z, 0, 0, 0);
                s[qi][kvb] = __builtin_amdgcn_mfma_f32_16x16x32_bf16(qf[qi][1], kf1[kvb], z, 0, 0, 0);
            }
        // ---- p = E * exp(s); pack to per-wave LDS (C -> A layout) ----
#pragma unroll
        for (int qi = 0; qi < 2; qi++)
#pragma unroll
            for (int kvb = 0; kvb < 4; kvb++) {
                const ushort* ep = (const ushort*)&ev2[qi][kvb];
#pragma unroll
                for (int r = 0; r < 4; r++) {
                    const float p = b2f(ep[r]) * __expf(s[qi][kvb][r]);
                    lsum[qi][r] += p;
                    myp[(qi * 16 + quad * 4 + r) * 72 + kvb * 16 + ln] =
                        (short)f2b_fast(p);
                }
            }
        // ---- V fragments from LDS ----
        bf16x8 vf[4][2];
#pragma unroll
        for (int nd = 0; nd < 4; nd++)
#pragma unroll
            for (int kc = 0; kc < 2; kc++)
                vf[nd][kc] = *(bf16x8*)&Vs[(nd * 16 + ln) * 72 + kc * 32 + quad * 8];
        // ---- P A-fragments (same-wave LDS round trip, in-order DS) ----
        bf16x8 pa[2][2];
#pragma unroll
        for (int qi = 0; qi < 2; qi++)
#pragma unroll
            for (int kc = 0; kc < 2; kc++)
                pa[qi][kc] = *(bf16x8*)&myp[(qi * 16 + ln) * 72 + kc * 32 + quad * 8];
        // ---- O += P V ----
#pragma unroll
        for (int qi = 0; qi < 2; qi++)
#pragma unroll
            for (int kc = 0; kc < 2; kc++)
#pragma unroll
                for (int nd = 0; nd < 4; nd++)
                    O[qi][nd] = __builtin_amdgcn_mfma_f32_16x16x32_bf16(
                                    pa[qi][kc], vf[nd][kc], O[qi][nd], 0, 0, 0);
    }

    // row-sum reduce across the 16 lanes of each quad-row group
#pragma unroll
    for (int qi = 0; qi < 2; qi++)
#pragma unroll
        for (int r = 0; r < 4; r++) {
            float v = lsum[qi][r];
            v += __shfl_xor(v, 1, 16);
            v += __shfl_xor(v, 2, 16);
            v += __shfl_xor(v, 4, 16);
            v += __shfl_xor(v, 8, 16);
            lsum[qi][r] = 1.0f / v;
        }
    // write output in-place over q, [B,H,N,D] layout
#pragma unroll
    for (int qi = 0; qi < 2; qi++)
#pragma unroll
        for (int nd = 0; nd < 4; nd++)
#pragma unroll
            for (int r = 0; r < 4; r++) {
                qp[(size_t)(qw0 + qi * 16 + quad * 4 + r) * HD + nd * 16 + ln] =
                    f2b(O[qi][nd][r] * lsum[qi][r]);
            }
}

// =====================================================================
// Kernel 3: output projection -> d_out.  grid = (M/128, 8)
// A = attn output [B,H,N,D] bf16 (gathered), W = Wo bf16 plane.
// m97-style mainloop with global_load_lds.
// =====================================================================
__global__ __launch_bounds__(256) void gemm_out(
        const ushort* __restrict__ ao, const ushort* __restrict__ Wob,
        const float* __restrict__ bias, float* __restrict__ out) {
    __shared__ ushort As[LDSZ];
    __shared__ ushort Bs[LDSZ];
    const int m0 = blockIdx.x * 128;
    const int n0 = blockIdx.y * 128;
    const int t = threadIdx.x, lane = t & 63, wave = t >> 6;
    const int ln = lane & 15, quad = lane >> 4;
    const int wm = wave & 1, wn = wave >> 1;

    const int e0 = wave * 128 + lane;
    const int e1 = e0 + 64;
    const int bb = m0 >> 11;               // batch (block fits in one batch)
    const int nbase = m0 & 2047;
    // A chunk (row, c) at k0: ao[(bb*16 + k0>>6)*131072 + (nbase+row)*64 + (k0&32) + c*8]
    const ushort* gA0 = ao + ((size_t)bb << 21) +
                        (size_t)(nbase + (e0 >> 2)) * 64 + (e0 & 3) * 8;
    const ushort* gA1 = ao + ((size_t)bb << 21) +
                        (size_t)(nbase + (e1 >> 2)) * 64 + (e1 & 3) * 8;
    const ushort* gB0 = Wob + (size_t)(n0 + (e0 >> 2)) * 1024 + (e0 & 3) * 8;
    const ushort* gB1 = Wob + (size_t)(n0 + (e1 >> 2)) * 1024 + (e1 & 3) * 8;
    ushort* lA0 = As + wave * 1024;
    ushort* lA1 = lA0 + 512;
    ushort* lB0 = Bs + wave * 1024;
    ushort* lB1 = lB0 + 512;

    f32x4 acc[4][4];
#pragma unroll
    for (int i = 0; i < 4; i++)
#pragma unroll
        for (int j = 0; j < 4; j++) acc[i][j] = (f32x4){0.f, 0.f, 0.f, 0.f};

    for (int k0 = 0; k0 < 1024; k0 += 32) {
        const size_t aoff = ((size_t)(k0 >> 6) << 17) + (k0 & 32);
        __syncthreads();
        gload16(gA0 + aoff, lA0);
        gload16(gA1 + aoff, lA1);
        gload16(gB0 + k0, lB0);
        gload16(gB1 + k0, lB1);
        __syncthreads();
        bf16x8 af[4], bfr[4];
#pragma unroll
        for (int i = 0; i < 4; i++)
            af[i]  = *(bf16x8*)&As[(wm * 64 + i * 16 + ln) * 32 + quad * 8];
#pragma unroll
        for (int j = 0; j < 4; j++)
            bfr[j] = *(bf16x8*)&Bs[(wn * 64 + j * 16 + ln) * 32 + quad * 8];
#pragma unroll
        for (int i = 0; i < 4; i++)
#pragma unroll
            for (int j = 0; j < 4; j++)
                acc[i][j] = __builtin_amdgcn_mfma_f32_16x16x32_bf16(
                                af[i], bfr[j], acc[i][j], 0, 0, 0);
    }

#pragma unroll
    for (int j = 0; j < 4; j++) {
        const int o = n0 + wn * 64 + j * 16 + ln;
        const float bval = bias[o];
#pragma unroll
        for (int i = 0; i < 4; i++) {
            const int mg = m0 + wm * 64 + i * 16 + quad * 4;
#pragma unroll
            for (int r = 0; r < 4; r++)
                out[(size_t)(mg + r) * EMB + o] = acc[i][j][r] + bval;
        }
    }
}

// =====================================================================
extern "C" void kernel_launch(void* const* d_in, const int* in_sizes, int n_in,
                              void* d_out, int out_size, void* d_ws, size_t ws_size,
                              hipStream_t stream) {
    const float* x    = (const float*)d_in[0];
    const float* dist = (const float*)d_in[1];
    const float* Wq   = (const float*)d_in[2];
    const float* bq   = (const float*)d_in[3];
    const float* Wk   = (const float*)d_in[4];
    const float* bk   = (const float*)d_in[5];
    const float* Wv   = (const float*)d_in[6];
    const float* bv   = (const float*)d_in[7];
    const float* Wo   = (const float*)d_in[8];
    const float* bo   = (const float*)d_in[9];
    const float* dw   = (const float*)d_in[10];
    const float* db   = (const float*)d_in[11];

    const size_t PLANE = (size_t)8192 * 1024;   // elems per [M,C] bf16 buffer
    ushort* qb = (ushort*)d_ws;                 // [B,H,N,D] bf16, later attn out
    ushort* kb = qb + PLANE;                    // [B,H,N,D] bf16
    ushort* xb = kb + PLANE;                    // x as bf16 [8192][1024]
    ushort* Wb = xb + PLANE;                    // [Wq;Wk;Wv;Wo] bf16, 4 x 1M elems
    // d_out is fp32 [8192,1024] = 33.6 MB; use as scratch before gemm_out:
    ushort* vT = (ushort*)d_out;                // [B,H,D,N] bf16 (16.8 MB)
    ushort* Eb = vT + PLANE;                    // permuted E table (8.4 MB)

    dim3 blk(256);
    conv_x       <<<dim3(4096),      blk, 0, stream>>>(x, xb);
    conv_w4      <<<dim3(512, 4),    blk, 0, stream>>>(Wq, Wk, Wv, Wo, Wb);
    bias_exp_perm<<<dim3(8, 128),    blk, 0, stream>>>(dist, dw, db, Eb);
    gemm_qkv     <<<dim3(64, 24),    blk, 0, stream>>>(xb, Wb, bq, bk, bv,
                                                       qb, kb, vT);
    attn         <<<dim3(16, 16, 4), blk, 0, stream>>>(qb, kb, vT, Eb);
    gemm_out     <<<dim3(64, 8),     blk, 0, stream>>>(qb, Wb + 3 * (size_t)(1 << 20),
                                                       bo, (float*)d_out);
}